// Round 1
// baseline (792.864 us; speedup 1.0000x reference)
//
#include <hip/hip_runtime.h>
#include <math.h>

#define PI_F 3.14159265358979323846f

// Fixed problem dims
constexpr int Bq = 8, Lq = 1024, Sq = 1024, Hq = 8, Dq = 64;

// ---------------------------------------------------------------------------
// Kernel 1: quantum feature-map states.
// For each (b,l,h): angles a_q = tanh(x . w_q + b_q) * pi  (q=0..3)
// diag[d] = exp(-0.5i * arg[d]), arg[d] = sum_q a_q z_q(d) + sum_p a_p a_{p+1} z_p z_{p+1}
// state[d] = diag[d] * (1/16) * sum_e (-1)^{popc(d&e)} diag[e]   (NL=2 closed form)
// Output layout: st[(b*H + h)*L + l][16] as float2 (re, im).
// ---------------------------------------------------------------------------
__global__ __launch_bounds__(256) void k_states(
    const float* __restrict__ x, const float* __restrict__ w,
    const float* __restrict__ bias, float2* __restrict__ st)
{
  __shared__ float lw[4][64];
  __shared__ float lb[4];
  int t = threadIdx.x;
  lw[t >> 6][t & 63] = w[t];
  if (t < 4) lb[t] = bias[t];
  __syncthreads();

  int n = blockIdx.x * 256 + t;   // flat (b,l,h); 65536 items
  const float4* xp = (const float4*)(x + (size_t)n * 64);
  float a0 = lb[0], a1 = lb[1], a2 = lb[2], a3 = lb[3];
#pragma unroll
  for (int i = 0; i < 16; ++i) {
    float4 v = xp[i];
    a0 += v.x * lw[0][4*i] + v.y * lw[0][4*i+1] + v.z * lw[0][4*i+2] + v.w * lw[0][4*i+3];
    a1 += v.x * lw[1][4*i] + v.y * lw[1][4*i+1] + v.z * lw[1][4*i+2] + v.w * lw[1][4*i+3];
    a2 += v.x * lw[2][4*i] + v.y * lw[2][4*i+1] + v.z * lw[2][4*i+2] + v.w * lw[2][4*i+3];
    a3 += v.x * lw[3][4*i] + v.y * lw[3][4*i+1] + v.z * lw[3][4*i+2] + v.w * lw[3][4*i+3];
  }
  a0 = tanhf(a0) * PI_F;
  a1 = tanhf(a1) * PI_F;
  a2 = tanhf(a2) * PI_F;
  a3 = tanhf(a3) * PI_F;
  float p01 = a0 * a1, p12 = a1 * a2, p23 = a2 * a3;

  float dr[16], di[16];
#pragma unroll
  for (int d = 0; d < 16; ++d) {
    // wire 0 is MSB: z_q(d) = 1 - 2*((d >> (3-q)) & 1)
    float s0 = (d & 8) ? -1.f : 1.f;
    float s1 = (d & 4) ? -1.f : 1.f;
    float s2 = (d & 2) ? -1.f : 1.f;
    float s3 = (d & 1) ? -1.f : 1.f;
    float arg = a0*s0 + a1*s1 + a2*s2 + a3*s3
              + p01*s0*s1 + p12*s1*s2 + p23*s2*s3;
    float sn, cs;
    sincosf(0.5f * arg, &sn, &cs);
    dr[d] = cs; di[d] = -sn;
  }

  // 16-point Walsh-Hadamard: hr[d] = sum_e (-1)^{popc(d&e)} dr[e]
  float hr[16], hi[16];
#pragma unroll
  for (int i = 0; i < 16; ++i) { hr[i] = dr[i]; hi[i] = di[i]; }
#pragma unroll
  for (int stp = 1; stp < 16; stp <<= 1) {
#pragma unroll
    for (int i = 0; i < 16; ++i) {
      if (!(i & stp)) {
        float xr = hr[i], yr = hr[i + stp];
        hr[i] = xr + yr; hr[i + stp] = xr - yr;
        float xi = hi[i], yi = hi[i + stp];
        hi[i] = xi + yi; hi[i + stp] = xi - yi;
      }
    }
  }

  int b = n >> 13, l = (n >> 3) & 1023, h = n & 7;
  float2* op = st + ((size_t)(b * Hq + h) * Lq + l) * 16;
#pragma unroll
  for (int d = 0; d < 16; ++d) {
    float rr = (dr[d] * hr[d] - di[d] * hi[d]) * 0.0625f;
    float ii = (dr[d] * hi[d] + di[d] * hr[d]) * 0.0625f;
    op[d] = make_float2(rr, ii);
  }
}

// ---------------------------------------------------------------------------
// Kernel 2: raw fidelity scores + row sums.
// score[l,s] = |sum_d sq[l,d] * conj(sk[s,d])|^2
// Block: 256 threads, 128 q-rows (2 per thread), all 1024 s.
// sk read straight from global (L2-resident, 16-lane broadcast).
// Writes raw scores into attn region; rowsum[bh*L + l] into ws.
// ---------------------------------------------------------------------------
__global__ __launch_bounds__(256) void k_scores(
    const float4* __restrict__ sq, const float4* __restrict__ sk,
    float* __restrict__ attn, float* __restrict__ rowsum)
{
  int bid = blockIdx.x;                // 512 blocks
  int xcd = bid & 7, idx = bid >> 3;   // XCD-contiguous bh mapping
  int bh = (xcd << 3) | (idx >> 3);
  int l0 = (idx & 7) << 7;             // l-tile of 128
  int t = threadIdx.x;
  int r = t >> 2, lane4 = t & 3;
  int row0 = l0 + r, row1 = row0 + 64;

  const float4* q0p = sq + ((size_t)bh * Lq + row0) * 8;
  const float4* q1p = sq + ((size_t)bh * Lq + row1) * 8;
  float4 q0[8], q1[8];
#pragma unroll
  for (int i = 0; i < 8; ++i) { q0[i] = q0p[i]; q1[i] = q1p[i]; }

  const float4* kb = sk + (size_t)bh * Lq * 8;
  float* a0p = attn + ((size_t)bh * Lq + row0) * Sq;
  float* a1p = attn + ((size_t)bh * Lq + row1) * Sq;
  float sum0 = 0.f, sum1 = 0.f;

  for (int j = 0; j < 64; ++j) {
    int sb = j * 16 + lane4 * 4;       // 4 consecutive s per thread
    float o0[4], o1[4];
#pragma unroll
    for (int k = 0; k < 4; ++k) {
      const float4* kp = kb + (size_t)(sb + k) * 8;
      float fr0 = 0.f, fi0 = 0.f, fr1 = 0.f, fi1 = 0.f;
#pragma unroll
      for (int i = 0; i < 8; ++i) {
        float4 kk = kp[i];             // (re,im,re,im) dims 2i,2i+1
        float4 qa = q0[i], qb = q1[i];
        fr0 += qa.x*kk.x + qa.y*kk.y + qa.z*kk.z + qa.w*kk.w;
        fi0 += qa.y*kk.x - qa.x*kk.y + qa.w*kk.z - qa.z*kk.w;
        fr1 += qb.x*kk.x + qb.y*kk.y + qb.z*kk.z + qb.w*kk.w;
        fi1 += qb.y*kk.x - qb.x*kk.y + qb.w*kk.z - qb.z*kk.w;
      }
      float sc0 = fr0*fr0 + fi0*fi0;
      float sc1 = fr1*fr1 + fi1*fi1;
      o0[k] = sc0; o1[k] = sc1;
      sum0 += sc0; sum1 += sc1;
    }
    *(float4*)(a0p + sb) = make_float4(o0[0], o0[1], o0[2], o0[3]);
    *(float4*)(a1p + sb) = make_float4(o1[0], o1[1], o1[2], o1[3]);
  }
  sum0 += __shfl_xor(sum0, 1); sum0 += __shfl_xor(sum0, 2);
  sum1 += __shfl_xor(sum1, 1); sum1 += __shfl_xor(sum1, 2);
  if (lane4 == 0) {
    rowsum[(size_t)bh * Lq + row0] = sum0;
    rowsum[(size_t)bh * Lq + row1] = sum1;
  }
}

// ---------------------------------------------------------------------------
// Kernel 3: normalize attn in place + context = W . V
// Block: 128 threads, 64 q-rows, tiles of 128 s.
// Phase 1: read raw, scale by 1/(rowsum+1e-6), write back, stash W^T in LDS.
// Phase 2: 4 rows x 8 d register tile; v from global (L2-resident per bh).
// ---------------------------------------------------------------------------
__global__ __launch_bounds__(128) void k_ctx(
    const float* __restrict__ vvals, const float* __restrict__ rowsum,
    float* __restrict__ attn, float* __restrict__ ctx)
{
  __shared__ float wT[128 * 68];       // [s_local][row], stride 68 (bank-safe)
  int bid = blockIdx.x;                // 1024 blocks
  int xcd = bid & 7, idx = bid >> 3;   // idx in [0,128)
  int bh = (xcd << 3) | (idx >> 4);
  int l0 = (idx & 15) << 6;            // l-tile of 64
  int b = bh >> 3, h = bh & 7;
  int t = threadIdx.x;

  // phase-1 mapping: one row, 64 consecutive s per thread
  int prow = t >> 1;
  int pc0 = (t & 1) << 6;
  float rinv = 1.f / (rowsum[(size_t)bh * Lq + l0 + prow] + 1e-6f);
  float* arow = attn + ((size_t)bh * Lq + l0 + prow) * Sq;

  // phase-2 mapping: 4 rows x 8 d per thread
  int rg = t >> 3;                     // [0,16)
  int dg = t & 7;                      // [0,8)
  float acc[4][8];
#pragma unroll
  for (int i = 0; i < 4; ++i)
#pragma unroll
    for (int j = 0; j < 8; ++j) acc[i][j] = 0.f;

  const float* vbase = vvals + ((size_t)b * Sq * Hq + h) * 64 + dg * 8;

  for (int s0 = 0; s0 < Sq; s0 += 128) {
    // ---- phase 1: normalize + write back + transpose into LDS ----
#pragma unroll
    for (int j = 0; j < 16; ++j) {
      int c = pc0 + j * 4;
      float4 raw = *(const float4*)(arow + s0 + c);
      float4 wv = make_float4(raw.x * rinv, raw.y * rinv, raw.z * rinv, raw.w * rinv);
      *(float4*)(arow + s0 + c) = wv;
      wT[(c + 0) * 68 + prow] = wv.x;
      wT[(c + 1) * 68 + prow] = wv.y;
      wT[(c + 2) * 68 + prow] = wv.z;
      wT[(c + 3) * 68 + prow] = wv.w;
    }
    __syncthreads();
    // ---- phase 2: context accumulation ----
#pragma unroll 4
    for (int s = 0; s < 128; ++s) {
      float4 wv = *(const float4*)&wT[s * 68 + rg * 4];
      const float* vp = vbase + (size_t)(s0 + s) * (Hq * 64);
      float4 va = *(const float4*)vp;
      float4 vb = *(const float4*)(vp + 4);
      acc[0][0] += wv.x * va.x; acc[0][1] += wv.x * va.y;
      acc[0][2] += wv.x * va.z; acc[0][3] += wv.x * va.w;
      acc[0][4] += wv.x * vb.x; acc[0][5] += wv.x * vb.y;
      acc[0][6] += wv.x * vb.z; acc[0][7] += wv.x * vb.w;
      acc[1][0] += wv.y * va.x; acc[1][1] += wv.y * va.y;
      acc[1][2] += wv.y * va.z; acc[1][3] += wv.y * va.w;
      acc[1][4] += wv.y * vb.x; acc[1][5] += wv.y * vb.y;
      acc[1][6] += wv.y * vb.z; acc[1][7] += wv.y * vb.w;
      acc[2][0] += wv.z * va.x; acc[2][1] += wv.z * va.y;
      acc[2][2] += wv.z * va.z; acc[2][3] += wv.z * va.w;
      acc[2][4] += wv.z * vb.x; acc[2][5] += wv.z * vb.y;
      acc[2][6] += wv.z * vb.z; acc[2][7] += wv.z * vb.w;
      acc[3][0] += wv.w * va.x; acc[3][1] += wv.w * va.y;
      acc[3][2] += wv.w * va.z; acc[3][3] += wv.w * va.w;
      acc[3][4] += wv.w * vb.x; acc[3][5] += wv.w * vb.y;
      acc[3][6] += wv.w * vb.z; acc[3][7] += wv.w * vb.w;
    }
    __syncthreads();
  }

#pragma unroll
  for (int i = 0; i < 4; ++i) {
    int row = l0 + rg * 4 + i;
    float* cp = ctx + (((size_t)b * Lq + row) * Hq + h) * 64 + dg * 8;
    *(float4*)cp       = make_float4(acc[i][0], acc[i][1], acc[i][2], acc[i][3]);
    *(float4*)(cp + 4) = make_float4(acc[i][4], acc[i][5], acc[i][6], acc[i][7]);
  }
}

// ---------------------------------------------------------------------------
extern "C" void kernel_launch(void* const* d_in, const int* in_sizes, int n_in,
                              void* d_out, int out_size, void* d_ws, size_t ws_size,
                              hipStream_t stream) {
  const float* q  = (const float*)d_in[0];
  const float* k  = (const float*)d_in[1];
  const float* v  = (const float*)d_in[2];
  const float* wq = (const float*)d_in[3];
  const float* bq = (const float*)d_in[4];
  const float* wk = (const float*)d_in[5];
  const float* bk = (const float*)d_in[6];

  float* out  = (float*)d_out;
  float* ctx  = out;                    // [B,L,H,D] = 4,194,304 floats
  float* attn = out + 4194304;          // [B,H,L,S] = 67,108,864 floats

  // States live temporarily in the context region (exactly fills it); the
  // context is only written by k_ctx, which never reads the states.
  float2* SQ = (float2*)out;            // 1,048,576 float2
  float2* SK = (float2*)(out + 2097152);

  float* rowsum = (float*)d_ws;         // 65,536 floats (256 KB)

  hipLaunchKernelGGL(k_states, dim3(256), dim3(256), 0, stream, q, wq, bq, SQ);
  hipLaunchKernelGGL(k_states, dim3(256), dim3(256), 0, stream, k, wk, bk, SK);
  hipLaunchKernelGGL(k_scores, dim3(512), dim3(256), 0, stream,
                     (const float4*)SQ, (const float4*)SK, attn, rowsum);
  hipLaunchKernelGGL(k_ctx, dim3(1024), dim3(128), 0, stream, v, rowsum, attn, ctx);
}

// Round 2
// 224.398 us; speedup vs baseline: 3.5333x; 3.5333x over previous
//
#include <hip/hip_runtime.h>
#include <math.h>

#define PI_F 3.14159265358979323846f

constexpr int Bq = 8, Lq = 1024, Sq = 1024, Hq = 8, Dq = 64;

typedef short short8 __attribute__((ext_vector_type(8)));
typedef float f4v __attribute__((ext_vector_type(4)));
typedef unsigned short ushort_t;

static __device__ __forceinline__ ushort_t f2bf(float x) {
  union { float f; unsigned u; } v; v.f = x;
  unsigned r = v.u + 0x7fffu + ((v.u >> 16) & 1u);   // RNE
  return (ushort_t)(r >> 16);
}
static __device__ __forceinline__ float bf2f(ushort_t b) {
  union { unsigned u; float f; } v; v.u = ((unsigned)b) << 16;
  return v.f;
}
static __device__ __forceinline__ f4v mfma16(short8 a, short8 b, f4v c) {
  return __builtin_amdgcn_mfma_f32_16x16x32_bf16(a, b, c, 0, 0, 0);
}
// q~' from q~: pairs (re,im) -> (im,-re); bf16 negate = sign-bit flip
static __device__ __forceinline__ short8 primef(short8 q) {
  short8 r;
#pragma unroll
  for (int i = 0; i < 4; ++i) {
    r[2 * i]     = q[2 * i + 1];
    r[2 * i + 1] = (short)(((ushort_t)q[2 * i]) ^ 0x8000u);
  }
  return r;
}

// ===========================================================================
// NEW PATH
// ===========================================================================
// k_states2: per item (b,l,h) compute 16 complex state comps, emit interleaved
// real vector q~[32] as bf16 hi + lo.  Layout: [(b*8+h)*1024 + l][32].
__global__ __launch_bounds__(256) void k_states2(
    const float* __restrict__ x, const float* __restrict__ w,
    const float* __restrict__ bias, ushort_t* __restrict__ outH,
    ushort_t* __restrict__ outL)
{
  __shared__ float lw[4][64];
  __shared__ float lb[4];
  int t = threadIdx.x;
  lw[t >> 6][t & 63] = w[t];
  if (t < 4) lb[t] = bias[t];
  __syncthreads();

  int n = blockIdx.x * 256 + t;
  const float4* xp = (const float4*)(x + (size_t)n * 64);
  float a0 = lb[0], a1 = lb[1], a2 = lb[2], a3 = lb[3];
#pragma unroll
  for (int i = 0; i < 16; ++i) {
    float4 v = xp[i];
    a0 += v.x * lw[0][4*i] + v.y * lw[0][4*i+1] + v.z * lw[0][4*i+2] + v.w * lw[0][4*i+3];
    a1 += v.x * lw[1][4*i] + v.y * lw[1][4*i+1] + v.z * lw[1][4*i+2] + v.w * lw[1][4*i+3];
    a2 += v.x * lw[2][4*i] + v.y * lw[2][4*i+1] + v.z * lw[2][4*i+2] + v.w * lw[2][4*i+3];
    a3 += v.x * lw[3][4*i] + v.y * lw[3][4*i+1] + v.z * lw[3][4*i+2] + v.w * lw[3][4*i+3];
  }
  a0 = tanhf(a0) * PI_F; a1 = tanhf(a1) * PI_F;
  a2 = tanhf(a2) * PI_F; a3 = tanhf(a3) * PI_F;
  float p01 = a0 * a1, p12 = a1 * a2, p23 = a2 * a3;

  float dr[16], di[16];
#pragma unroll
  for (int d = 0; d < 16; ++d) {
    float s0 = (d & 8) ? -1.f : 1.f;
    float s1 = (d & 4) ? -1.f : 1.f;
    float s2 = (d & 2) ? -1.f : 1.f;
    float s3 = (d & 1) ? -1.f : 1.f;
    float arg = a0*s0 + a1*s1 + a2*s2 + a3*s3
              + p01*s0*s1 + p12*s1*s2 + p23*s2*s3;
    float sn, cs;
    sincosf(0.5f * arg, &sn, &cs);
    dr[d] = cs; di[d] = -sn;
  }
  float hr[16], hi[16];
#pragma unroll
  for (int i = 0; i < 16; ++i) { hr[i] = dr[i]; hi[i] = di[i]; }
#pragma unroll
  for (int stp = 1; stp < 16; stp <<= 1) {
#pragma unroll
    for (int i = 0; i < 16; ++i) {
      if (!(i & stp)) {
        float xr = hr[i], yr = hr[i + stp];
        hr[i] = xr + yr; hr[i + stp] = xr - yr;
        float xi = hi[i], yi = hi[i + stp];
        hi[i] = xi + yi; hi[i + stp] = xi - yi;
      }
    }
  }

  unsigned uh[16], ul[16];
#pragma unroll
  for (int d = 0; d < 16; ++d) {
    float rr = (dr[d] * hr[d] - di[d] * hi[d]) * 0.0625f;
    float ii = (dr[d] * hi[d] + di[d] * hr[d]) * 0.0625f;
    ushort_t rh = f2bf(rr), ih = f2bf(ii);
    ushort_t rl = f2bf(rr - bf2f(rh)), il = f2bf(ii - bf2f(ih));
    uh[d] = (unsigned)rh | ((unsigned)ih << 16);
    ul[d] = (unsigned)rl | ((unsigned)il << 16);
  }
  int b = n >> 13, l = (n >> 3) & 1023, h = n & 7;
  size_t rb = ((size_t)(b * Hq + h) * Lq + l) * 32;
  uint4* ph = (uint4*)(outH + rb);
  uint4* pl = (uint4*)(outL + rb);
#pragma unroll
  for (int i = 0; i < 4; ++i) {
    ph[i] = make_uint4(uh[4*i], uh[4*i+1], uh[4*i+2], uh[4*i+3]);
    pl[i] = make_uint4(ul[4*i], ul[4*i+1], ul[4*i+2], ul[4*i+3]);
  }
}

// k_vt: V [B][S][H][64] f32  ->  VT [bh][d][s] bf16 hi/lo (transposed per bh)
__global__ __launch_bounds__(256) void k_vt(
    const float* __restrict__ v, ushort_t* __restrict__ vtH,
    ushort_t* __restrict__ vtL)
{
  __shared__ float tile[64 * 68];
  int bid = blockIdx.x;
  int bh = bid >> 4, s0 = (bid & 15) << 6;
  int b = bh >> 3, h = bh & 7;
  int t = threadIdx.x;
  int sl = t >> 2, dq = (t & 3) << 4;
  const float4* src = (const float4*)(v + (((size_t)b * Sq + s0 + sl) * Hq + h) * 64 + dq);
#pragma unroll
  for (int i = 0; i < 4; ++i)
    *(float4*)&tile[sl * 68 + dq + 4 * i] = src[i];
  __syncthreads();
  int d = t >> 2, sq = (t & 3) << 4;
  unsigned hw[8], lw2[8];
#pragma unroll
  for (int j = 0; j < 8; ++j) {
    float x0 = tile[(sq + 2*j)     * 68 + d];
    float x1 = tile[(sq + 2*j + 1) * 68 + d];
    ushort_t h0 = f2bf(x0), h1 = f2bf(x1);
    ushort_t l0 = f2bf(x0 - bf2f(h0)), l1 = f2bf(x1 - bf2f(h1));
    hw[j]  = (unsigned)h0 | ((unsigned)h1 << 16);
    lw2[j] = (unsigned)l0 | ((unsigned)l1 << 16);
  }
  size_t ob = ((size_t)bh * 64 + d) * 1024 + s0 + sq;
  uint4* oh = (uint4*)(vtH + ob);
  uint4* ol = (uint4*)(vtL + ob);
  oh[0] = make_uint4(hw[0], hw[1], hw[2], hw[3]);
  oh[1] = make_uint4(hw[4], hw[5], hw[6], hw[7]);
  ol[0] = make_uint4(lw2[0], lw2[1], lw2[2], lw2[3]);
  ol[1] = make_uint4(lw2[4], lw2[5], lw2[6], lw2[7]);
}

// k_fused: per (bh, 64-row l-tile): pass1 rowsums (hi-only fid), pass2
// split-3 fid -> normalize -> attn write -> W hi/lo to LDS -> split-3 PV.
__global__ __launch_bounds__(256) void k_fused(
    const ushort_t* __restrict__ QH, const ushort_t* __restrict__ QL,
    const ushort_t* __restrict__ KH, const ushort_t* __restrict__ KL,
    const ushort_t* __restrict__ VTH, const ushort_t* __restrict__ VTL,
    float* __restrict__ attn, float* __restrict__ ctx)
{
  __shared__ ushort_t WbufH[4][16 * 64];
  __shared__ ushort_t WbufL[4][16 * 64];
  int bid = blockIdx.x;
  int wg = ((bid & 7) << 7) | (bid >> 3);    // XCD swizzle (1024 % 8 == 0)
  int bh = wg >> 4;
  int l0 = (wg & 15) << 6;
  int t = threadIdx.x;
  int wv = t >> 6, lane = t & 63;
  int lh = lane & 15, g = lane >> 4;
  int ko = g << 3;

  int lrow = l0 + (wv << 4) + lh;
  size_t qoff = ((size_t)bh * Lq + lrow) * 32 + ko;
  short8 qh  = *(const short8*)(QH + qoff);
  short8 ql  = *(const short8*)(QL + qoff);
  short8 qph = primef(qh), qpl = primef(ql);

  const ushort_t* KHb = KH + (size_t)bh * Sq * 32;
  const ushort_t* KLb = KL + (size_t)bh * Sq * 32;
  const ushort_t* VHb = VTH + (size_t)bh * 64 * Sq;
  const ushort_t* VLb = VTL + (size_t)bh * 64 * Sq;

  f4v zero = {0.f, 0.f, 0.f, 0.f};

  // ---- pass 1: rowsum of |fid|^2, hi precision only ----
  float rsum = 0.f;
  for (int sf = 0; sf < 64; ++sf) {
    int s = (sf << 4) + lh;
    short8 kh = *(const short8*)(KHb + (size_t)s * 32 + ko);
    f4v fr = mfma16(kh, qh, zero);
    f4v fi = mfma16(kh, qph, zero);
#pragma unroll
    for (int r = 0; r < 4; ++r) rsum += fr[r] * fr[r] + fi[r] * fi[r];
  }
  rsum += __shfl_xor(rsum, 16);
  rsum += __shfl_xor(rsum, 32);
  float rinv = 1.f / (rsum + 1e-6f);

  // ---- pass 2 ----
  float* attnRow = attn + ((size_t)bh * Lq + lrow) * Sq;
  ushort_t* wbh = &WbufH[wv][0];
  ushort_t* wbl = &WbufL[wv][0];
  f4v pvacc[4];
#pragma unroll
  for (int i = 0; i < 4; ++i) pvacc[i] = zero;

  for (int c = 0; c < 16; ++c) {
    int s0 = c << 6;
#pragma unroll
    for (int f = 0; f < 4; ++f) {
      int sb = s0 + (f << 4);
      int srow = sb + lh;
      short8 kh = *(const short8*)(KHb + (size_t)srow * 32 + ko);
      short8 kl = *(const short8*)(KLb + (size_t)srow * 32 + ko);
      f4v fr = mfma16(kh, qh, zero);
      fr = mfma16(kl, qh, fr);
      fr = mfma16(kh, ql, fr);
      f4v fi = mfma16(kh, qph, zero);
      fi = mfma16(kl, qph, fi);
      fi = mfma16(kh, qpl, fi);
      float wv4[4];
#pragma unroll
      for (int r = 0; r < 4; ++r) {
        float sc = fr[r] * fr[r] + fi[r] * fi[r];
        wv4[r] = sc * rinv;
      }
      int sbase = sb + (g << 2);
      *(float4*)(attnRow + sbase) = make_float4(wv4[0], wv4[1], wv4[2], wv4[3]);
      ushort_t h0 = f2bf(wv4[0]), h1 = f2bf(wv4[1]),
               h2 = f2bf(wv4[2]), h3 = f2bf(wv4[3]);
      ushort_t e0 = f2bf(wv4[0] - bf2f(h0)), e1 = f2bf(wv4[1] - bf2f(h1)),
               e2 = f2bf(wv4[2] - bf2f(h2)), e3 = f2bf(wv4[3] - bf2f(h3));
      int sloc = (f << 4) + (g << 2);
      unsigned off = ((unsigned)lh << 7) + ((unsigned)sloc << 1);
      off ^= (unsigned)(lh & 7) << 4;
      *(uint2*)((char*)wbh + off) = make_uint2((unsigned)h0 | ((unsigned)h1 << 16),
                                               (unsigned)h2 | ((unsigned)h3 << 16));
      *(uint2*)((char*)wbl + off) = make_uint2((unsigned)e0 | ((unsigned)e1 << 16),
                                               (unsigned)e2 | ((unsigned)e3 << 16));
    }
    // PV for this chunk
#pragma unroll
    for (int ks = 0; ks < 2; ++ks) {
      unsigned aoff = ((unsigned)lh << 7) + (unsigned)((ks << 6) + (ko << 1));
      aoff ^= (unsigned)(lh & 7) << 4;
      short8 wh = *(const short8*)((char*)wbh + aoff);
      short8 wl = *(const short8*)((char*)wbl + aoff);
      int svt = s0 + (ks << 5) + ko;
#pragma unroll
      for (int f2 = 0; f2 < 4; ++f2) {
        int d = (f2 << 4) + lh;
        short8 vh = *(const short8*)(VHb + ((size_t)d << 10) + svt);
        short8 vl = *(const short8*)(VLb + ((size_t)d << 10) + svt);
        pvacc[f2] = mfma16(wh, vh, pvacc[f2]);
        pvacc[f2] = mfma16(wl, vh, pvacc[f2]);
        pvacc[f2] = mfma16(wh, vl, pvacc[f2]);
      }
    }
  }

  int b = bh >> 3, h = bh & 7;
#pragma unroll
  for (int f2 = 0; f2 < 4; ++f2) {
    int d = (f2 << 4) + lh;
#pragma unroll
    for (int r = 0; r < 4; ++r) {
      int l = l0 + (wv << 4) + (g << 2) + r;
      ctx[(((size_t)b * Lq + l) * Hq + h) * 64 + d] = pvacc[f2][r];
    }
  }
}

// ===========================================================================
// FALLBACK PATH (round-1 kernels, used only if ws_size < 32 MB)
// ===========================================================================
__global__ __launch_bounds__(256) void k_states(
    const float* __restrict__ x, const float* __restrict__ w,
    const float* __restrict__ bias, float2* __restrict__ st)
{
  __shared__ float lw[4][64];
  __shared__ float lb[4];
  int t = threadIdx.x;
  lw[t >> 6][t & 63] = w[t];
  if (t < 4) lb[t] = bias[t];
  __syncthreads();
  int n = blockIdx.x * 256 + t;
  const float4* xp = (const float4*)(x + (size_t)n * 64);
  float a0 = lb[0], a1 = lb[1], a2 = lb[2], a3 = lb[3];
#pragma unroll
  for (int i = 0; i < 16; ++i) {
    float4 v = xp[i];
    a0 += v.x * lw[0][4*i] + v.y * lw[0][4*i+1] + v.z * lw[0][4*i+2] + v.w * lw[0][4*i+3];
    a1 += v.x * lw[1][4*i] + v.y * lw[1][4*i+1] + v.z * lw[1][4*i+2] + v.w * lw[1][4*i+3];
    a2 += v.x * lw[2][4*i] + v.y * lw[2][4*i+1] + v.z * lw[2][4*i+2] + v.w * lw[2][4*i+3];
    a3 += v.x * lw[3][4*i] + v.y * lw[3][4*i+1] + v.z * lw[3][4*i+2] + v.w * lw[3][4*i+3];
  }
  a0 = tanhf(a0) * PI_F; a1 = tanhf(a1) * PI_F;
  a2 = tanhf(a2) * PI_F; a3 = tanhf(a3) * PI_F;
  float p01 = a0 * a1, p12 = a1 * a2, p23 = a2 * a3;
  float dr[16], di[16];
#pragma unroll
  for (int d = 0; d < 16; ++d) {
    float s0 = (d & 8) ? -1.f : 1.f;
    float s1 = (d & 4) ? -1.f : 1.f;
    float s2 = (d & 2) ? -1.f : 1.f;
    float s3 = (d & 1) ? -1.f : 1.f;
    float arg = a0*s0 + a1*s1 + a2*s2 + a3*s3 + p01*s0*s1 + p12*s1*s2 + p23*s2*s3;
    float sn, cs;
    sincosf(0.5f * arg, &sn, &cs);
    dr[d] = cs; di[d] = -sn;
  }
  float hr[16], hi[16];
#pragma unroll
  for (int i = 0; i < 16; ++i) { hr[i] = dr[i]; hi[i] = di[i]; }
#pragma unroll
  for (int stp = 1; stp < 16; stp <<= 1) {
#pragma unroll
    for (int i = 0; i < 16; ++i) {
      if (!(i & stp)) {
        float xr = hr[i], yr = hr[i + stp];
        hr[i] = xr + yr; hr[i + stp] = xr - yr;
        float xi = hi[i], yi = hi[i + stp];
        hi[i] = xi + yi; hi[i + stp] = xi - yi;
      }
    }
  }
  int b = n >> 13, l = (n >> 3) & 1023, h = n & 7;
  float2* op = st + ((size_t)(b * Hq + h) * Lq + l) * 16;
#pragma unroll
  for (int d = 0; d < 16; ++d) {
    float rr = (dr[d] * hr[d] - di[d] * hi[d]) * 0.0625f;
    float ii = (dr[d] * hi[d] + di[d] * hr[d]) * 0.0625f;
    op[d] = make_float2(rr, ii);
  }
}

__global__ __launch_bounds__(256) void k_scores(
    const float4* __restrict__ sq, const float4* __restrict__ sk,
    float* __restrict__ attn, float* __restrict__ rowsum)
{
  int bid = blockIdx.x;
  int xcd = bid & 7, idx = bid >> 3;
  int bh = (xcd << 3) | (idx >> 3);
  int l0 = (idx & 7) << 7;
  int t = threadIdx.x;
  int r = t >> 2, lane4 = t & 3;
  int row0 = l0 + r, row1 = row0 + 64;
  const float4* q0p = sq + ((size_t)bh * Lq + row0) * 8;
  const float4* q1p = sq + ((size_t)bh * Lq + row1) * 8;
  float4 q0[8], q1[8];
#pragma unroll
  for (int i = 0; i < 8; ++i) { q0[i] = q0p[i]; q1[i] = q1p[i]; }
  const float4* kb = sk + (size_t)bh * Lq * 8;
  float* a0p = attn + ((size_t)bh * Lq + row0) * Sq;
  float* a1p = attn + ((size_t)bh * Lq + row1) * Sq;
  float sum0 = 0.f, sum1 = 0.f;
  for (int j = 0; j < 64; ++j) {
    int sb = j * 16 + lane4 * 4;
    float o0[4], o1[4];
#pragma unroll
    for (int k = 0; k < 4; ++k) {
      const float4* kp = kb + (size_t)(sb + k) * 8;
      float fr0 = 0.f, fi0 = 0.f, fr1 = 0.f, fi1 = 0.f;
#pragma unroll
      for (int i = 0; i < 8; ++i) {
        float4 kk = kp[i];
        float4 qa = q0[i], qb = q1[i];
        fr0 += qa.x*kk.x + qa.y*kk.y + qa.z*kk.z + qa.w*kk.w;
        fi0 += qa.y*kk.x - qa.x*kk.y + qa.w*kk.z - qa.z*kk.w;
        fr1 += qb.x*kk.x + qb.y*kk.y + qb.z*kk.z + qb.w*kk.w;
        fi1 += qb.y*kk.x - qb.x*kk.y + qb.w*kk.z - qb.z*kk.w;
      }
      float sc0 = fr0*fr0 + fi0*fi0;
      float sc1 = fr1*fr1 + fi1*fi1;
      o0[k] = sc0; o1[k] = sc1;
      sum0 += sc0; sum1 += sc1;
    }
    *(float4*)(a0p + sb) = make_float4(o0[0], o0[1], o0[2], o0[3]);
    *(float4*)(a1p + sb) = make_float4(o1[0], o1[1], o1[2], o1[3]);
  }
  sum0 += __shfl_xor(sum0, 1); sum0 += __shfl_xor(sum0, 2);
  sum1 += __shfl_xor(sum1, 1); sum1 += __shfl_xor(sum1, 2);
  if (lane4 == 0) {
    rowsum[(size_t)bh * Lq + row0] = sum0;
    rowsum[(size_t)bh * Lq + row1] = sum1;
  }
}

__global__ __launch_bounds__(128) void k_ctx(
    const float* __restrict__ vvals, const float* __restrict__ rowsum,
    float* __restrict__ attn, float* __restrict__ ctx)
{
  __shared__ float wT[128 * 68];
  int bid = blockIdx.x;
  int xcd = bid & 7, idx = bid >> 3;
  int bh = (xcd << 3) | (idx >> 4);
  int l0 = (idx & 15) << 6;
  int b = bh >> 3, h = bh & 7;
  int t = threadIdx.x;
  int prow = t >> 1;
  int pc0 = (t & 1) << 6;
  float rinv = 1.f / (rowsum[(size_t)bh * Lq + l0 + prow] + 1e-6f);
  float* arow = attn + ((size_t)bh * Lq + l0 + prow) * Sq;
  int rg = t >> 3;
  int dg = t & 7;
  float acc[4][8];
#pragma unroll
  for (int i = 0; i < 4; ++i)
#pragma unroll
    for (int j = 0; j < 8; ++j) acc[i][j] = 0.f;
  const float* vbase = vvals + ((size_t)b * Sq * Hq + h) * 64 + dg * 8;
  for (int s0 = 0; s0 < Sq; s0 += 128) {
#pragma unroll
    for (int j = 0; j < 16; ++j) {
      int c = pc0 + j * 4;
      float4 raw = *(const float4*)(arow + s0 + c);
      float4 wv = make_float4(raw.x * rinv, raw.y * rinv, raw.z * rinv, raw.w * rinv);
      *(float4*)(arow + s0 + c) = wv;
      wT[(c + 0) * 68 + prow] = wv.x;
      wT[(c + 1) * 68 + prow] = wv.y;
      wT[(c + 2) * 68 + prow] = wv.z;
      wT[(c + 3) * 68 + prow] = wv.w;
    }
    __syncthreads();
#pragma unroll 4
    for (int s = 0; s < 128; ++s) {
      float4 wv = *(const float4*)&wT[s * 68 + rg * 4];
      const float* vp = vbase + (size_t)(s0 + s) * (Hq * 64);
      float4 va = *(const float4*)vp;
      float4 vb = *(const float4*)(vp + 4);
      acc[0][0] += wv.x * va.x; acc[0][1] += wv.x * va.y;
      acc[0][2] += wv.x * va.z; acc[0][3] += wv.x * va.w;
      acc[0][4] += wv.x * vb.x; acc[0][5] += wv.x * vb.y;
      acc[0][6] += wv.x * vb.z; acc[0][7] += wv.x * vb.w;
      acc[1][0] += wv.y * va.x; acc[1][1] += wv.y * va.y;
      acc[1][2] += wv.y * va.z; acc[1][3] += wv.y * va.w;
      acc[1][4] += wv.y * vb.x; acc[1][5] += wv.y * vb.y;
      acc[1][6] += wv.y * vb.z; acc[1][7] += wv.y * vb.w;
      acc[2][0] += wv.z * va.x; acc[2][1] += wv.z * va.y;
      acc[2][2] += wv.z * va.z; acc[2][3] += wv.z * va.w;
      acc[2][4] += wv.z * vb.x; acc[2][5] += wv.z * vb.y;
      acc[2][6] += wv.z * vb.z; acc[2][7] += wv.z * vb.w;
      acc[3][0] += wv.w * va.x; acc[3][1] += wv.w * va.y;
      acc[3][2] += wv.w * va.z; acc[3][3] += wv.w * va.w;
      acc[3][4] += wv.w * vb.x; acc[3][5] += wv.w * vb.y;
      acc[3][6] += wv.w * vb.z; acc[3][7] += wv.w * vb.w;
    }
    __syncthreads();
  }
#pragma unroll
  for (int i = 0; i < 4; ++i) {
    int row = l0 + rg * 4 + i;
    float* cp = ctx + (((size_t)b * Lq + row) * Hq + h) * 64 + dg * 8;
    *(float4*)cp       = make_float4(acc[i][0], acc[i][1], acc[i][2], acc[i][3]);
    *(float4*)(cp + 4) = make_float4(acc[i][4], acc[i][5], acc[i][6], acc[i][7]);
  }
}

// ===========================================================================
extern "C" void kernel_launch(void* const* d_in, const int* in_sizes, int n_in,
                              void* d_out, int out_size, void* d_ws, size_t ws_size,
                              hipStream_t stream) {
  const float* q  = (const float*)d_in[0];
  const float* k  = (const float*)d_in[1];
  const float* v  = (const float*)d_in[2];
  const float* wq = (const float*)d_in[3];
  const float* bq = (const float*)d_in[4];
  const float* wk = (const float*)d_in[5];
  const float* bk = (const float*)d_in[6];

  float* out  = (float*)d_out;
  float* ctx  = out;                    // [B,L,H,D]  = 4,194,304 floats
  float* attn = out + 4194304;          // [B,H,L,S]  = 67,108,864 floats

  if (ws_size >= (size_t)33554432) {
    char* w = (char*)d_ws;
    ushort_t* QH  = (ushort_t*)(w);
    ushort_t* QL  = (ushort_t*)(w + (size_t)4  * 1024 * 1024);
    ushort_t* KH  = (ushort_t*)(w + (size_t)8  * 1024 * 1024);
    ushort_t* KL  = (ushort_t*)(w + (size_t)12 * 1024 * 1024);
    ushort_t* VTH = (ushort_t*)(w + (size_t)16 * 1024 * 1024);
    ushort_t* VTL = (ushort_t*)(w + (size_t)24 * 1024 * 1024);

    hipLaunchKernelGGL(k_states2, dim3(256), dim3(256), 0, stream, q, wq, bq, QH, QL);
    hipLaunchKernelGGL(k_states2, dim3(256), dim3(256), 0, stream, k, wk, bk, KH, KL);
    hipLaunchKernelGGL(k_vt, dim3(1024), dim3(256), 0, stream, v, VTH, VTL);
    hipLaunchKernelGGL(k_fused, dim3(1024), dim3(256), 0, stream,
                       QH, QL, KH, KL, VTH, VTL, attn, ctx);
  } else {
    float2* SQ = (float2*)out;
    float2* SK = (float2*)(out + 2097152);
    float* rowsum = (float*)d_ws;
    hipLaunchKernelGGL(k_states, dim3(256), dim3(256), 0, stream, q, wq, bq, SQ);
    hipLaunchKernelGGL(k_states, dim3(256), dim3(256), 0, stream, k, wk, bk, SK);
    hipLaunchKernelGGL(k_scores, dim3(512), dim3(256), 0, stream,
                       (const float4*)SQ, (const float4*)SK, attn, rowsum);
    hipLaunchKernelGGL(k_ctx, dim3(1024), dim3(128), 0, stream, v, rowsum, attn, ctx);
  }
}

// Round 3
// 220.600 us; speedup vs baseline: 3.5941x; 1.0172x over previous
//
#include <hip/hip_runtime.h>
#include <math.h>

#define PI_F 3.14159265358979323846f

constexpr int Bq = 8, Lq = 1024, Sq = 1024, Hq = 8, Dq = 64;

typedef short short8 __attribute__((ext_vector_type(8)));
typedef float f4v __attribute__((ext_vector_type(4)));
typedef unsigned short ushort_t;

static __device__ __forceinline__ ushort_t f2bf(float x) {
  union { float f; unsigned u; } v; v.f = x;
  unsigned r = v.u + 0x7fffu + ((v.u >> 16) & 1u);   // RNE
  return (ushort_t)(r >> 16);
}
static __device__ __forceinline__ float bf2f(ushort_t b) {
  union { unsigned u; float f; } v; v.u = ((unsigned)b) << 16;
  return v.f;
}
static __device__ __forceinline__ f4v mfma16(short8 a, short8 b, f4v c) {
  return __builtin_amdgcn_mfma_f32_16x16x32_bf16(a, b, c, 0, 0, 0);
}
// q~' from q~: pairs (re,im) -> (im,-re); bf16 negate = sign-bit flip
static __device__ __forceinline__ short8 primef(short8 q) {
  short8 r;
#pragma unroll
  for (int i = 0; i < 4; ++i) {
    r[2 * i]     = q[2 * i + 1];
    r[2 * i + 1] = (short)(((ushort_t)q[2 * i]) ^ 0x8000u);
  }
  return r;
}

// ---------------------------------------------------------------------------
// k_states2: per item (b,l,h): angles -> diag -> WHT -> state; emit
// interleaved real vector q~[32] as bf16 hi + lo.  [(b*8+h)*1024 + l][32].
// ---------------------------------------------------------------------------
__global__ __launch_bounds__(256) void k_states2(
    const float* __restrict__ x, const float* __restrict__ w,
    const float* __restrict__ bias, ushort_t* __restrict__ outH,
    ushort_t* __restrict__ outL)
{
  __shared__ float lw[4][64];
  __shared__ float lb[4];
  int t = threadIdx.x;
  lw[t >> 6][t & 63] = w[t];
  if (t < 4) lb[t] = bias[t];
  __syncthreads();

  int n = blockIdx.x * 256 + t;
  const float4* xp = (const float4*)(x + (size_t)n * 64);
  float a0 = lb[0], a1 = lb[1], a2 = lb[2], a3 = lb[3];
#pragma unroll
  for (int i = 0; i < 16; ++i) {
    float4 v = xp[i];
    a0 += v.x * lw[0][4*i] + v.y * lw[0][4*i+1] + v.z * lw[0][4*i+2] + v.w * lw[0][4*i+3];
    a1 += v.x * lw[1][4*i] + v.y * lw[1][4*i+1] + v.z * lw[1][4*i+2] + v.w * lw[1][4*i+3];
    a2 += v.x * lw[2][4*i] + v.y * lw[2][4*i+1] + v.z * lw[2][4*i+2] + v.w * lw[2][4*i+3];
    a3 += v.x * lw[3][4*i] + v.y * lw[3][4*i+1] + v.z * lw[3][4*i+2] + v.w * lw[3][4*i+3];
  }
  a0 = tanhf(a0) * PI_F; a1 = tanhf(a1) * PI_F;
  a2 = tanhf(a2) * PI_F; a3 = tanhf(a3) * PI_F;
  float p01 = a0 * a1, p12 = a1 * a2, p23 = a2 * a3;

  float dr[16], di[16];
#pragma unroll
  for (int d = 0; d < 16; ++d) {
    float s0 = (d & 8) ? -1.f : 1.f;
    float s1 = (d & 4) ? -1.f : 1.f;
    float s2 = (d & 2) ? -1.f : 1.f;
    float s3 = (d & 1) ? -1.f : 1.f;
    float arg = a0*s0 + a1*s1 + a2*s2 + a3*s3
              + p01*s0*s1 + p12*s1*s2 + p23*s2*s3;
    float sn, cs;
    sincosf(0.5f * arg, &sn, &cs);
    dr[d] = cs; di[d] = -sn;
  }
  float hr[16], hi[16];
#pragma unroll
  for (int i = 0; i < 16; ++i) { hr[i] = dr[i]; hi[i] = di[i]; }
#pragma unroll
  for (int stp = 1; stp < 16; stp <<= 1) {
#pragma unroll
    for (int i = 0; i < 16; ++i) {
      if (!(i & stp)) {
        float xr = hr[i], yr = hr[i + stp];
        hr[i] = xr + yr; hr[i + stp] = xr - yr;
        float xi = hi[i], yi = hi[i + stp];
        hi[i] = xi + yi; hi[i + stp] = xi - yi;
      }
    }
  }

  unsigned uh[16], ul[16];
#pragma unroll
  for (int d = 0; d < 16; ++d) {
    float rr = (dr[d] * hr[d] - di[d] * hi[d]) * 0.0625f;
    float ii = (dr[d] * hi[d] + di[d] * hr[d]) * 0.0625f;
    ushort_t rh = f2bf(rr), ih = f2bf(ii);
    ushort_t rl = f2bf(rr - bf2f(rh)), il = f2bf(ii - bf2f(ih));
    uh[d] = (unsigned)rh | ((unsigned)ih << 16);
    ul[d] = (unsigned)rl | ((unsigned)il << 16);
  }
  int b = n >> 13, l = (n >> 3) & 1023, h = n & 7;
  size_t rb = ((size_t)(b * Hq + h) * Lq + l) * 32;
  uint4* ph = (uint4*)(outH + rb);
  uint4* pl = (uint4*)(outL + rb);
#pragma unroll
  for (int i = 0; i < 4; ++i) {
    ph[i] = make_uint4(uh[4*i], uh[4*i+1], uh[4*i+2], uh[4*i+3]);
    pl[i] = make_uint4(ul[4*i], ul[4*i+1], ul[4*i+2], ul[4*i+3]);
  }
}

// ---------------------------------------------------------------------------
// k_vt: V [B][S][H][64] f32  ->  VT [bh][d][s] bf16 hi/lo (transposed per bh)
// ---------------------------------------------------------------------------
__global__ __launch_bounds__(256) void k_vt(
    const float* __restrict__ v, ushort_t* __restrict__ vtH,
    ushort_t* __restrict__ vtL)
{
  __shared__ float tile[64 * 68];
  int bid = blockIdx.x;
  int bh = bid >> 4, s0 = (bid & 15) << 6;
  int b = bh >> 3, h = bh & 7;
  int t = threadIdx.x;
  int sl = t >> 2, dq = (t & 3) << 4;
  const float4* src = (const float4*)(v + (((size_t)b * Sq + s0 + sl) * Hq + h) * 64 + dq);
#pragma unroll
  for (int i = 0; i < 4; ++i)
    *(float4*)&tile[sl * 68 + dq + 4 * i] = src[i];
  __syncthreads();
  int d = t >> 2, sq = (t & 3) << 4;
  unsigned hw[8], lw2[8];
#pragma unroll
  for (int j = 0; j < 8; ++j) {
    float x0 = tile[(sq + 2*j)     * 68 + d];
    float x1 = tile[(sq + 2*j + 1) * 68 + d];
    ushort_t h0 = f2bf(x0), h1 = f2bf(x1);
    ushort_t l0 = f2bf(x0 - bf2f(h0)), l1 = f2bf(x1 - bf2f(h1));
    hw[j]  = (unsigned)h0 | ((unsigned)h1 << 16);
    lw2[j] = (unsigned)l0 | ((unsigned)l1 << 16);
  }
  size_t ob = ((size_t)bh * 64 + d) * 1024 + s0 + sq;
  uint4* oh = (uint4*)(vtH + ob);
  uint4* ol = (uint4*)(vtL + ob);
  oh[0] = make_uint4(hw[0], hw[1], hw[2], hw[3]);
  oh[1] = make_uint4(hw[4], hw[5], hw[6], hw[7]);
  ol[0] = make_uint4(lw2[0], lw2[1], lw2[2], lw2[3]);
  ol[1] = make_uint4(lw2[4], lw2[5], lw2[6], lw2[7]);
}

// ---------------------------------------------------------------------------
// k_fused2: 2048 blocks, 256 threads.  Block = (bh, 32-row l-tile).
// Wave wv: rg = wv&1 (16-row group), sh = wv>>1 (512-s half).
// Pass1: half rowsums (hi-only fid MFMA) -> LDS exchange -> rinv.
// Pass2 per 64-s chunk: split-3 fid -> normalize -> nt attn write
//  -> W hi/lo in swizzled LDS -> split-3 PV MFMA.
// Epilogue: s-half PV reduce via LDS (overlays Wbuf), nt ctx write.
// ---------------------------------------------------------------------------
__global__ __launch_bounds__(256, 6) void k_fused2(
    const ushort_t* __restrict__ QH, const ushort_t* __restrict__ QL,
    const ushort_t* __restrict__ KH, const ushort_t* __restrict__ KL,
    const ushort_t* __restrict__ VTH, const ushort_t* __restrict__ VTL,
    const float* __restrict__ /*unused*/, float* __restrict__ attn,
    float* __restrict__ ctx)
{
  __shared__ char uni[16384];           // Wbuf hi(8K)+lo(8K); redbuf overlays
  __shared__ float rs_buf[2][32];

  int bid = blockIdx.x;                 // 2048 (2048 % 8 == 0 -> bijective)
  int xcd = bid & 7, idx = bid >> 3;    // idx in [0,256)
  int bh = (xcd << 3) | (idx >> 5);     // 8 bh per XCD, l-tiles consecutive
  int l0 = (idx & 31) << 5;             // 32-row tile
  int t = threadIdx.x;
  int wv = t >> 6, lane = t & 63;
  int rg = wv & 1, sh = wv >> 1;
  int lh = lane & 15, g = lane >> 4, ko = g << 3;
  int sb0 = sh << 9;

  int lrow = l0 + (rg << 4) + lh;
  size_t qoff = ((size_t)bh * Lq + lrow) * 32 + ko;
  short8 qh  = *(const short8*)(QH + qoff);
  short8 ql  = *(const short8*)(QL + qoff);
  short8 qph = primef(qh), qpl = primef(ql);

  const ushort_t* KHb = KH + (size_t)bh * Sq * 32;
  const ushort_t* KLb = KL + (size_t)bh * Sq * 32;
  const ushort_t* VHb = VTH + (size_t)bh * 64 * Sq;
  const ushort_t* VLb = VTL + (size_t)bh * 64 * Sq;

  f4v zero = {0.f, 0.f, 0.f, 0.f};

  // ---- pass 1: half rowsum, hi-only ----
  float rsum = 0.f;
  for (int sf = 0; sf < 32; ++sf) {
    int s = sb0 + (sf << 4) + lh;
    short8 kh = *(const short8*)(KHb + (size_t)s * 32 + ko);
    f4v fr = mfma16(kh, qh, zero);
    f4v fi = mfma16(kh, qph, zero);
#pragma unroll
    for (int r = 0; r < 4; ++r) rsum += fr[r]*fr[r] + fi[r]*fi[r];
  }
  rsum += __shfl_xor(rsum, 16);
  rsum += __shfl_xor(rsum, 32);
  if (lane < 16) rs_buf[sh][(rg << 4) + lh] = rsum;
  __syncthreads();
  float rinv = 1.f / (rs_buf[0][(rg << 4) + lh] + rs_buf[1][(rg << 4) + lh] + 1e-6f);

  // ---- pass 2 ----
  float* attnRow = attn + ((size_t)bh * Lq + lrow) * Sq;
  char* wbh = uni + wv * 2048;
  char* wbl = uni + 8192 + wv * 2048;
  f4v pv[4] = {zero, zero, zero, zero};

  for (int c = 0; c < 8; ++c) {
    int s0 = sb0 + (c << 6);
#pragma unroll
    for (int f = 0; f < 4; ++f) {
      int srow = s0 + (f << 4) + lh;
      short8 kh = *(const short8*)(KHb + (size_t)srow * 32 + ko);
      short8 kl = *(const short8*)(KLb + (size_t)srow * 32 + ko);
      f4v fr = mfma16(kh, qh, zero);
      fr = mfma16(kl, qh, fr);
      fr = mfma16(kh, ql, fr);
      f4v fi = mfma16(kh, qph, zero);
      fi = mfma16(kl, qph, fi);
      fi = mfma16(kh, qpl, fi);
      f4v wv4;
#pragma unroll
      for (int r = 0; r < 4; ++r)
        wv4[r] = (fr[r]*fr[r] + fi[r]*fi[r]) * rinv;
      __builtin_nontemporal_store(wv4, (f4v*)(attnRow + s0 + (f << 4) + (g << 2)));
      // hi = truncation (exact prefix), lo = RNE of residual
      union { float f; unsigned u; } c0, c1, c2, c3;
      c0.f = wv4[0]; c1.f = wv4[1]; c2.f = wv4[2]; c3.f = wv4[3];
      unsigned t0 = c0.u & 0xFFFF0000u, t1 = c1.u & 0xFFFF0000u;
      unsigned t2 = c2.u & 0xFFFF0000u, t3 = c3.u & 0xFFFF0000u;
      union { unsigned u; float f; } b0, b1, b2, b3;
      b0.u = t0; b1.u = t1; b2.u = t2; b3.u = t3;
      ushort_t e0 = f2bf(wv4[0] - b0.f), e1 = f2bf(wv4[1] - b1.f);
      ushort_t e2 = f2bf(wv4[2] - b2.f), e3 = f2bf(wv4[3] - b3.f);
      unsigned off = ((unsigned)lh << 7) + ((unsigned)((f << 4) + (g << 2)) << 1);
      off ^= (unsigned)(lh & 7) << 4;
      *(uint2*)(wbh + off) = make_uint2((t0 >> 16) | t1, (t2 >> 16) | t3);
      *(uint2*)(wbl + off) = make_uint2((unsigned)e0 | ((unsigned)e1 << 16),
                                        (unsigned)e2 | ((unsigned)e3 << 16));
    }
#pragma unroll
    for (int ks = 0; ks < 2; ++ks) {
      unsigned aoff = ((unsigned)lh << 7) + (unsigned)((ks << 6) + (ko << 1));
      aoff ^= (unsigned)(lh & 7) << 4;
      short8 wh = *(const short8*)(wbh + aoff);
      short8 wl = *(const short8*)(wbl + aoff);
      int svt = s0 + (ks << 5) + ko;
#pragma unroll
      for (int f2 = 0; f2 < 4; ++f2) {
        int d = (f2 << 4) + lh;
        short8 vh = *(const short8*)(VHb + ((size_t)d << 10) + svt);
        short8 vl = *(const short8*)(VLb + ((size_t)d << 10) + svt);
        pv[f2] = mfma16(wh, vh, pv[f2]);
        pv[f2] = mfma16(wl, vh, pv[f2]);
        pv[f2] = mfma16(wh, vl, pv[f2]);
      }
    }
  }

  // ---- epilogue: reduce s-halves, write ctx ----
  __syncthreads();                      // all Wbuf consumers done
  f4v* red = (f4v*)uni;                 // [rg*4+f2][lane] -> 8 KB
  if (sh == 1) {
#pragma unroll
    for (int f2 = 0; f2 < 4; ++f2) red[((rg << 2) + f2) * 64 + lane] = pv[f2];
  }
  __syncthreads();
  if (sh == 0) {
    int b = bh >> 3, h = bh & 7;
#pragma unroll
    for (int f2 = 0; f2 < 4; ++f2) {
      f4v tot = pv[f2] + red[((rg << 2) + f2) * 64 + lane];
      int d = (f2 << 4) + lh;
#pragma unroll
      for (int r = 0; r < 4; ++r) {
        int l = l0 + (rg << 4) + (g << 2) + r;
        __builtin_nontemporal_store(
            tot[r], ctx + (((size_t)b * Lq + l) * Hq + h) * 64 + d);
      }
    }
  }
}

// ===========================================================================
extern "C" void kernel_launch(void* const* d_in, const int* in_sizes, int n_in,
                              void* d_out, int out_size, void* d_ws, size_t ws_size,
                              hipStream_t stream) {
  const float* q  = (const float*)d_in[0];
  const float* k  = (const float*)d_in[1];
  const float* v  = (const float*)d_in[2];
  const float* wq = (const float*)d_in[3];
  const float* bq = (const float*)d_in[4];
  const float* wk = (const float*)d_in[5];
  const float* bk = (const float*)d_in[6];

  float* out  = (float*)d_out;
  float* ctx  = out;                    // [B,L,H,D]  = 4,194,304 floats
  float* attn = out + 4194304;          // [B,H,L,S]  = 67,108,864 floats

  char* wsb = (char*)d_ws;
  ushort_t* QH  = (ushort_t*)(wsb);
  ushort_t* QL  = (ushort_t*)(wsb + (size_t)4  * 1024 * 1024);
  ushort_t* KH  = (ushort_t*)(wsb + (size_t)8  * 1024 * 1024);
  ushort_t* KL  = (ushort_t*)(wsb + (size_t)12 * 1024 * 1024);
  ushort_t* VTH = (ushort_t*)(wsb + (size_t)16 * 1024 * 1024);
  ushort_t* VTL = (ushort_t*)(wsb + (size_t)24 * 1024 * 1024);

  hipLaunchKernelGGL(k_states2, dim3(256), dim3(256), 0, stream, q, wq, bq, QH, QL);
  hipLaunchKernelGGL(k_states2, dim3(256), dim3(256), 0, stream, k, wk, bk, KH, KL);
  hipLaunchKernelGGL(k_vt, dim3(1024), dim3(256), 0, stream, v, VTH, VTL);
  hipLaunchKernelGGL(k_fused2, dim3(2048), dim3(256), 0, stream,
                     QH, QL, KH, KL, VTH, VTL, (const float*)nullptr, attn, ctx);
}